// Round 4
// baseline (70.427 us; speedup 1.0000x reference)
//
#include <hip/hip_runtime.h>

// B=256, N=512 cells, G=117 genes, CH=25 conv channels.
// Conv as MFMA: O1^T(640x64cells) = W_big^T(640x64i) @ img(64i x 64cells)
//   j = ch*25+p (625 real, pad 640), i = 7x7 pixel (49 real; i=49 -> ones column
//   carrying b_emph; pad 64). ReLU+bf16 -> A2 (chunk-major LDS, 2 halves of 320).
// mm2: out(64cells x 128genes) += A2 @ W_reg^T, K=640, 8 waves (2x4) of 32x32 tiles.
// Epilogue: acc -> C[64][128] f32 LDS -> contiguous coalesced dword stores of the
// block's 29952-B cell chunk; spot partials read from C (no post-store barrier).
// out1 (pure glob broadcast, 61 MB) is a separate streaming-store kernel.

typedef __attribute__((ext_vector_type(16))) float f32x16;
typedef __attribute__((ext_vector_type(8))) short short8;

#define WB_OFF    0          // 163840 B : W_reg bf16 B-frags [40 ksteps][4 wc][64][8]
#define WBIG_OFF  163840     // 81920 B  : W_big^T bf16 A-frags [20 jt][4 s][64][8]
#define GLOB_OFF  245760     // 1024 B   : glob[256]
#define SPOT_OFF  246784     // 1 MB     : [256][8][128] f32 partials

#define SPOT_OUT_OFF 0
#define CELL_OUT_OFF 29952
#define OUT1_OUT_OFF 15365376

__device__ __forceinline__ unsigned short f2bf(float x) {
  unsigned int u = __builtin_bit_cast(unsigned int, x);
  u = (u + 0x7FFFu + ((u >> 16) & 1u)) >> 16;   // RNE
  return (unsigned short)u;
}

// blocks 0..255: glob ; 256..335: wbig (jt x s) ; 336..495: wb (sg x wc)
__global__ __launch_bounds__(128) void prep_kernel(
    const float* __restrict__ spot_images, const float* __restrict__ W_patch,
    const float* __restrict__ b_patch, const float* __restrict__ W_glob,
    const float* __restrict__ b_glob, const float* __restrict__ W_reg,
    const float* __restrict__ W_emph, const float* __restrict__ b_emph,
    unsigned short* __restrict__ wb, unsigned short* __restrict__ wbig,
    float* __restrict__ glob) {
  int bid = blockIdx.x;
  int tid = threadIdx.x;
  if (bid < 256) {
    __shared__ float red[75];
    if (tid < 75) {
      int token = tid / 3;
      int chan = tid - token * 3;
      int ty = token / 5, tx = token - ty * 5;
      const float* img = spot_images + bid * 784 + (ty * 5) * 28 + tx * 5;
      float a = 0.f;
      #pragma unroll
      for (int i = 0; i < 5; ++i)
        #pragma unroll
        for (int j = 0; j < 5; ++j)
          a = fmaf(img[i * 28 + j], W_patch[chan * 25 + i * 5 + j], a);
      a += b_patch[chan];
      red[tid] = a * W_glob[tid];
    }
    __syncthreads();
    if (tid == 0) {
      float s = b_glob[0];
      for (int k = 0; k < 75; ++k) s += red[k];
      glob[bid] = (s > 0.f) ? s : expm1f(s);
    }
  } else if (bid < 336) {
    int idx = bid - 256;               // jt*4 + s
    int jt = idx >> 2, s = idx & 3;
    if (tid < 64) {
      int j = jt * 32 + (tid & 31);
      int h = tid >> 5;
      unsigned short hv[8];
      #pragma unroll
      for (int jj = 0; jj < 8; ++jj) {
        int i = s * 16 + h * 8 + jj;
        float val = 0.f;
        if (j < 625) {
          int ch = j / 25, p = j % 25;
          int oy = p / 5, ox = p - oy * 5;
          if (i < 49) {
            int iy = i / 7, ix = i - iy * 7;
            int ky = iy - oy, kx = ix - ox;
            if (ky >= 0 && ky < 3 && kx >= 0 && kx < 3)
              val = W_emph[ch * 9 + ky * 3 + kx];
          } else if (i == 49) {
            val = b_emph[ch];
          }
        }
        hv[jj] = f2bf(val);
      }
      unsigned int u[4];
      #pragma unroll
      for (int k = 0; k < 4; ++k)
        u[k] = (unsigned int)hv[2 * k] | ((unsigned int)hv[2 * k + 1] << 16);
      ((uint4*)wbig)[idx * 64 + tid] = make_uint4(u[0], u[1], u[2], u[3]);
    }
  } else {
    int idx = bid - 336;               // sg*4 + wc
    int sg = idx >> 2, wcp = idx & 3;
    if (tid < 64) {
      int g = wcp * 32 + (tid & 31);
      int h = tid >> 5;
      unsigned short hv[8];
      #pragma unroll
      for (int jj = 0; jj < 8; ++jj) {
        int k = sg * 16 + h * 8 + jj;
        float val = (g < 117 && k < 625) ? W_reg[g * 625 + k] : 0.f;
        hv[jj] = f2bf(val);
      }
      unsigned int u[4];
      #pragma unroll
      for (int k = 0; k < 4; ++k)
        u[k] = (unsigned int)hv[2 * k] | ((unsigned int)hv[2 * k + 1] << 16);
      ((uint4*)wb)[idx * 64 + tid] = make_uint4(u[0], u[1], u[2], u[3]);
    }
  }
}

// out1[b,:,:] = glob[b] broadcast: 1024 blocks, 4 per batch, float4 streams.
__global__ __launch_bounds__(256) void out1_bcast(
    const float* __restrict__ glob, float* __restrict__ out) {
  int bid = blockIdx.x;
  int b = bid >> 2, q = bid & 3;
  float gb = glob[b];
  float4 v = make_float4(gb, gb, gb, gb);
  float4* dst = (float4*)(out + OUT1_OUT_OFF + (size_t)b * 59904) + q * 3744;
  #pragma unroll 4
  for (int i = threadIdx.x; i < 3744; i += 256) dst[i] = v;
}

// One block = (batch b, 64-cell tile). 512 threads = 8 waves (wr 0..1 x wc 0..3).
__global__ __launch_bounds__(512) void main_kernel(
    const float* __restrict__ images, const float* __restrict__ b_reg,
    const unsigned short* __restrict__ wb, const unsigned short* __restrict__ wbig,
    const float* __restrict__ glob, float* __restrict__ out,
    float* __restrict__ spotp) {
  __shared__ char smem[49152];
  unsigned short* A2s = (unsigned short*)smem;             // 40960 B [jc][cell][8]
  unsigned short* imgbs = (unsigned short*)(smem + 40960); // 8192 B [kc][cell][8]
  float* C = (float*)smem;                                 // 32768 B [64][128], after mm
  int tid = threadIdx.x;
  int bid = blockIdx.x;
  int b = bid >> 3, tile = bid & 7;
  int n0 = tile * 64;

  // ---- stage img -> bf16 chunk-major LDS (i=49 -> 1.0 bias column) ----
  {
    int cell = tid & 63, kc = tid >> 6;
    const float* src = images + (size_t)(b * 512 + n0 + cell) * 49 + kc * 8;
    float v[8];
    #pragma unroll
    for (int j = 0; j < 8; ++j) v[j] = 0.f;
    if (kc < 6) {
      #pragma unroll
      for (int j = 0; j < 8; ++j) v[j] = src[j];
    } else if (kc == 6) {
      v[0] = src[0];
      v[1] = 1.0f;
    }
    unsigned int u[4];
    #pragma unroll
    for (int k = 0; k < 4; ++k)
      u[k] = (unsigned int)f2bf(v[2 * k]) | ((unsigned int)f2bf(v[2 * k + 1]) << 16);
    ((uint4*)imgbs)[kc * 64 + cell] = make_uint4(u[0], u[1], u[2], u[3]);
  }
  __syncthreads();

  int l = tid & 63;
  int wu = __builtin_amdgcn_readfirstlane(tid >> 6);
  int wr = wu >> 2, wc = wu & 3, ctw = wu & 1;
  int m = l & 31, hh = l >> 5;
  int cellw = ctw * 32 + m;
  const short8* imgb8 = (const short8*)imgbs;
  const short8* A2r = (const short8*)A2s;
  const short8* wb8 = (const short8*)wb;
  const short8* wbig8 = (const short8*)wbig;

  f32x16 acc;
  #pragma unroll
  for (int i = 0; i < 16; ++i) acc[i] = 0.f;

  for (int hf = 0; hf < 2; ++hf) {
    // ---- mm1: conv via MFMA, tiles T = wu, wu+8, wu+16 (ct = wu&1 fixed) ----
    #pragma unroll
    for (int t = 0; t < 3; ++t) {
      int T = wu + 8 * t;
      if (T < 20) {
        int jt = T >> 1;
        f32x16 o;
        #pragma unroll
        for (int i = 0; i < 16; ++i) o[i] = 0.f;
        #pragma unroll
        for (int s = 0; s < 4; ++s) {
          short8 a = wbig8[((hf * 10 + jt) * 4 + s) * 64 + l];
          short8 bf = imgb8[(2 * s + hh) * 64 + cellw];
          o = __builtin_amdgcn_mfma_f32_32x32x16_bf16(a, bf, o, 0, 0, 0);
        }
        // relu + pack: reg quad q holds j = jt*32 + 8q + 4*hh + {0..3}, col cellw
        #pragma unroll
        for (int q = 0; q < 4; ++q) {
          unsigned int u0 = (unsigned int)f2bf(fmaxf(o[4 * q + 0], 0.f)) |
                            ((unsigned int)f2bf(fmaxf(o[4 * q + 1], 0.f)) << 16);
          unsigned int u1 = (unsigned int)f2bf(fmaxf(o[4 * q + 2], 0.f)) |
                            ((unsigned int)f2bf(fmaxf(o[4 * q + 3], 0.f)) << 16);
          int sidx = (jt * 4 + q) * 512 + cellw * 8 + hh * 4;
          *(uint2*)(A2s + sidx) = make_uint2(u0, u1);
        }
      }
    }
    __syncthreads();
    // ---- mm2: acc += A2(64x320) @ wb(320x128) for this half ----
    for (int s2 = 0; s2 < 20; ++s2) {
      short8 af = A2r[(2 * s2 + hh) * 64 + wr * 32 + m];
      short8 bf = wb8[((hf * 20 + s2) * 4 + wc) * 64 + l];
      acc = __builtin_amdgcn_mfma_f32_32x32x16_bf16(af, bf, acc, 0, 0, 0);
    }
    __syncthreads();
  }

  // ---- epilogue: acc -> C[64][128] f32 LDS (banks conflict-free) ----
  float gb = glob[b];
  int g = wc * 32 + m;
  float br = (g < 117) ? b_reg[g] : 0.f;
  #pragma unroll
  for (int reg = 0; reg < 16; ++reg) {
    int n = wr * 32 + (reg & 3) + 8 * (reg >> 2) + 4 * hh;
    C[n * 128 + g] = fmaxf(acc[reg] + br + gb, 0.f);
  }
  __syncthreads();

  // contiguous coalesced readout of the block's 29952-B cell chunk
  size_t rowbase = (size_t)(b * 512 + n0);
  float* cellchunk = out + CELL_OUT_OFF + rowbase * 117;
  #pragma unroll
  for (int i = 0; i < 15; ++i) {
    int idx = i * 512 + tid;
    if (idx < 7488) {
      int n = idx / 117;
      int gg = idx - n * 117;
      cellchunk[idx] = C[n * 128 + gg];
    }
  }
  // spot partials straight from C (reads only; no barrier after global stores)
  if (tid < 128) {
    float s = 0.f;
    #pragma unroll 8
    for (int n = 0; n < 64; ++n) s += C[n * 128 + tid];
    spotp[(size_t)(b * 8 + tile) * 128 + tid] = s;
  }
}

// spot[b][g] = sum of 8 tile partials
__global__ __launch_bounds__(256) void spot_reduce(
    const float* __restrict__ spotp, float* __restrict__ out) {
  int idx = blockIdx.x * 256 + threadIdx.x;   // exactly 117*256 = 29952
  int b = idx / 117;
  int g = idx - b * 117;
  float s = 0.f;
  #pragma unroll
  for (int t = 0; t < 8; ++t) s += spotp[(size_t)(b * 8 + t) * 128 + g];
  out[SPOT_OUT_OFF + idx] = s;
}

extern "C" void kernel_launch(void* const* d_in, const int* in_sizes, int n_in,
                              void* d_out, int out_size, void* d_ws, size_t ws_size,
                              hipStream_t stream) {
  const float* images      = (const float*)d_in[0];
  const float* spot_images = (const float*)d_in[1];
  // d_in[2] = gene_expression (unused by the reference)
  const float* W_emph = (const float*)d_in[3];
  const float* b_emph = (const float*)d_in[4];
  const float* W_reg  = (const float*)d_in[5];
  const float* b_reg  = (const float*)d_in[6];
  const float* W_patch = (const float*)d_in[7];
  const float* b_patch = (const float*)d_in[8];
  const float* W_glob  = (const float*)d_in[9];
  const float* b_glob  = (const float*)d_in[10];
  float* out = (float*)d_out;

  unsigned short* wb   = (unsigned short*)((char*)d_ws + WB_OFF);
  unsigned short* wbig = (unsigned short*)((char*)d_ws + WBIG_OFF);
  float* glob  = (float*)((char*)d_ws + GLOB_OFF);
  float* spotp = (float*)((char*)d_ws + SPOT_OFF);

  prep_kernel<<<496, 128, 0, stream>>>(spot_images, W_patch, b_patch, W_glob,
                                       b_glob, W_reg, W_emph, b_emph, wb, wbig,
                                       glob);
  main_kernel<<<2048, 512, 0, stream>>>(images, b_reg, wb, wbig, glob, out,
                                        spotp);
  out1_bcast<<<1024, 256, 0, stream>>>(glob, out);
  spot_reduce<<<117, 256, 0, stream>>>(spotp, out);
}

// Round 5
// 64.731 us; speedup vs baseline: 1.0880x; 1.0880x over previous
//
#include <hip/hip_runtime.h>

// B=256, N=512 cells, G=117 genes, CH=25 conv channels.
// Conv as MFMA: O1^T(640x64cells) = W_big^T(640x64i) @ img(64i x 64cells)
//   j = ch*25+p (625 real, pad 640), i = 7x7 pixel (49 real; i=49 -> ones col
//   carrying b_emph; pad 64). ReLU+bf16 -> A2 chunk-major LDS, 2 halves of 320 j.
// mm2: out(64cells x 128genes) += A2 @ W_reg^T, K=640.
// 4 waves/block (256 thr): wave = 64 cells x 32 genes (2 accs) -> wb read 1x;
// mm1 wave computes both 32-cell tiles of a jt (a-frag reuse) -> wbig read 1x.
// Epilogue: C[64][128] f32 LDS; spot partials stored BEFORE bulk stores; then
// coalesced cell chunk + out1 (glob broadcast) streams. 50 KB LDS -> 3 blk/CU.

typedef __attribute__((ext_vector_type(16))) float f32x16;
typedef __attribute__((ext_vector_type(8))) short short8;

#define WB_OFF    0          // 163840 B : W_reg bf16 B-frags [40 ksteps][4 wc][64][8]
#define WBIG_OFF  163840     // 81920 B  : W_big^T bf16 A-frags [20 jt][4 s][64][8]
#define GLOB_OFF  245760     // 1024 B   : glob[256]
#define SPOT_OFF  246784     // 1 MB     : [256][8][128] f32 partials

#define SPOT_OUT_OFF 0
#define CELL_OUT_OFF 29952
#define OUT1_OUT_OFF 15365376

__device__ __forceinline__ unsigned short f2bf(float x) {
  unsigned int u = __builtin_bit_cast(unsigned int, x);
  u = (u + 0x7FFFu + ((u >> 16) & 1u)) >> 16;   // RNE
  return (unsigned short)u;
}

// blocks 0..255: glob ; 256..335: wbig (jt x s) ; 336..495: wb (sg x wc)
__global__ __launch_bounds__(128) void prep_kernel(
    const float* __restrict__ spot_images, const float* __restrict__ W_patch,
    const float* __restrict__ b_patch, const float* __restrict__ W_glob,
    const float* __restrict__ b_glob, const float* __restrict__ W_reg,
    const float* __restrict__ W_emph, const float* __restrict__ b_emph,
    unsigned short* __restrict__ wb, unsigned short* __restrict__ wbig,
    float* __restrict__ glob) {
  int bid = blockIdx.x;
  int tid = threadIdx.x;
  if (bid < 256) {
    __shared__ float red[75];
    if (tid < 75) {
      int token = tid / 3;
      int chan = tid - token * 3;
      int ty = token / 5, tx = token - ty * 5;
      const float* img = spot_images + bid * 784 + (ty * 5) * 28 + tx * 5;
      float a = 0.f;
      #pragma unroll
      for (int i = 0; i < 5; ++i)
        #pragma unroll
        for (int j = 0; j < 5; ++j)
          a = fmaf(img[i * 28 + j], W_patch[chan * 25 + i * 5 + j], a);
      a += b_patch[chan];
      red[tid] = a * W_glob[tid];
    }
    __syncthreads();
    if (tid == 0) {
      float s = b_glob[0];
      for (int k = 0; k < 75; ++k) s += red[k];
      glob[bid] = (s > 0.f) ? s : expm1f(s);
    }
  } else if (bid < 336) {
    int idx = bid - 256;               // jt*4 + s
    int jt = idx >> 2, s = idx & 3;
    if (tid < 64) {
      int j = jt * 32 + (tid & 31);
      int h = tid >> 5;
      unsigned short hv[8];
      #pragma unroll
      for (int jj = 0; jj < 8; ++jj) {
        int i = s * 16 + h * 8 + jj;
        float val = 0.f;
        if (j < 625) {
          int ch = j / 25, p = j % 25;
          int oy = p / 5, ox = p - oy * 5;
          if (i < 49) {
            int iy = i / 7, ix = i - iy * 7;
            int ky = iy - oy, kx = ix - ox;
            if (ky >= 0 && ky < 3 && kx >= 0 && kx < 3)
              val = W_emph[ch * 9 + ky * 3 + kx];
          } else if (i == 49) {
            val = b_emph[ch];
          }
        }
        hv[jj] = f2bf(val);
      }
      unsigned int u[4];
      #pragma unroll
      for (int k = 0; k < 4; ++k)
        u[k] = (unsigned int)hv[2 * k] | ((unsigned int)hv[2 * k + 1] << 16);
      ((uint4*)wbig)[idx * 64 + tid] = make_uint4(u[0], u[1], u[2], u[3]);
    }
  } else {
    int idx = bid - 336;               // sg*4 + wc
    int sg = idx >> 2, wcp = idx & 3;
    if (tid < 64) {
      int g = wcp * 32 + (tid & 31);
      int h = tid >> 5;
      unsigned short hv[8];
      #pragma unroll
      for (int jj = 0; jj < 8; ++jj) {
        int k = sg * 16 + h * 8 + jj;
        float val = (g < 117 && k < 625) ? W_reg[g * 625 + k] : 0.f;
        hv[jj] = f2bf(val);
      }
      unsigned int u[4];
      #pragma unroll
      for (int k = 0; k < 4; ++k)
        u[k] = (unsigned int)hv[2 * k] | ((unsigned int)hv[2 * k + 1] << 16);
      ((uint4*)wb)[idx * 64 + tid] = make_uint4(u[0], u[1], u[2], u[3]);
    }
  }
}

// One block = (batch b, 64-cell tile). 256 threads = 4 waves (wu = gene group).
__global__ __launch_bounds__(256, 3) void main_kernel(
    const float* __restrict__ images, const float* __restrict__ b_reg,
    const unsigned short* __restrict__ wb, const unsigned short* __restrict__ wbig,
    const float* __restrict__ glob, float* __restrict__ out,
    float* __restrict__ spotp) {
  __shared__ char smem[50176];
  unsigned short* A2s = (unsigned short*)smem;             // 40960 B [jc][cell][8]
  unsigned short* imgbs = (unsigned short*)(smem + 40960); // 8192 B [kc][cell][8]
  float* red = (float*)(smem + 49152);                     // 1024 B [2][128]
  float* C = (float*)smem;                                 // 32768 B [64][128]
  int tid = threadIdx.x;
  int bid = blockIdx.x;
  int b = bid >> 3, tile = bid & 7;
  int n0 = tile * 64;

  // ---- stage img -> bf16 chunk-major LDS (i=49 -> 1.0 bias column) ----
  #pragma unroll
  for (int u0 = 0; u0 < 2; ++u0) {
    int u = u0 * 256 + tid;
    int cell = u & 63, kc = u >> 6;
    const float* src = images + (size_t)(b * 512 + n0 + cell) * 49 + kc * 8;
    float v[8];
    #pragma unroll
    for (int j = 0; j < 8; ++j) v[j] = 0.f;
    if (kc < 6) {
      #pragma unroll
      for (int j = 0; j < 8; ++j) v[j] = src[j];
    } else if (kc == 6) {
      v[0] = src[0];
      v[1] = 1.0f;
    }
    unsigned int uu[4];
    #pragma unroll
    for (int k = 0; k < 4; ++k)
      uu[k] = (unsigned int)f2bf(v[2 * k]) | ((unsigned int)f2bf(v[2 * k + 1]) << 16);
    ((uint4*)imgbs)[kc * 64 + cell] = make_uint4(uu[0], uu[1], uu[2], uu[3]);
  }
  __syncthreads();

  int l = tid & 63;
  int wu = __builtin_amdgcn_readfirstlane(tid >> 6);   // 0..3 = gene col group
  int m = l & 31, hh = l >> 5;
  const short8* imgb8 = (const short8*)imgbs;
  const short8* A2r = (const short8*)A2s;
  const short8* wb8 = (const short8*)wb;
  const short8* wbig8 = (const short8*)wbig;

  f32x16 acc0, acc1;
  #pragma unroll
  for (int i = 0; i < 16; ++i) { acc0[i] = 0.f; acc1[i] = 0.f; }

  for (int hf = 0; hf < 2; ++hf) {
    // ---- mm1: wave wu does jt = wu, wu+4, wu+8 (<10); both cell tiles per jt
    #pragma unroll
    for (int ji = 0; ji < 3; ++ji) {
      int jt = wu + 4 * ji;
      if (jt < 10) {
        f32x16 o0, o1;
        #pragma unroll
        for (int i = 0; i < 16; ++i) { o0[i] = 0.f; o1[i] = 0.f; }
        #pragma unroll
        for (int s = 0; s < 4; ++s) {
          short8 a = wbig8[((hf * 10 + jt) * 4 + s) * 64 + l];
          short8 bt0 = imgb8[(2 * s + hh) * 64 + m];
          short8 bt1 = imgb8[(2 * s + hh) * 64 + 32 + m];
          o0 = __builtin_amdgcn_mfma_f32_32x32x16_bf16(a, bt0, o0, 0, 0, 0);
          o1 = __builtin_amdgcn_mfma_f32_32x32x16_bf16(a, bt1, o1, 0, 0, 0);
        }
        // relu+pack: quad q holds j = jt*32 + 8q + 4*hh + {0..3} for col cell
        #pragma unroll
        for (int q = 0; q < 4; ++q) {
          unsigned int u0 = (unsigned int)f2bf(fmaxf(o0[4 * q + 0], 0.f)) |
                            ((unsigned int)f2bf(fmaxf(o0[4 * q + 1], 0.f)) << 16);
          unsigned int u1 = (unsigned int)f2bf(fmaxf(o0[4 * q + 2], 0.f)) |
                            ((unsigned int)f2bf(fmaxf(o0[4 * q + 3], 0.f)) << 16);
          *(uint2*)(A2s + (jt * 4 + q) * 512 + m * 8 + hh * 4) = make_uint2(u0, u1);
          unsigned int w0 = (unsigned int)f2bf(fmaxf(o1[4 * q + 0], 0.f)) |
                            ((unsigned int)f2bf(fmaxf(o1[4 * q + 1], 0.f)) << 16);
          unsigned int w1 = (unsigned int)f2bf(fmaxf(o1[4 * q + 2], 0.f)) |
                            ((unsigned int)f2bf(fmaxf(o1[4 * q + 3], 0.f)) << 16);
          *(uint2*)(A2s + (jt * 4 + q) * 512 + (32 + m) * 8 + hh * 4) = make_uint2(w0, w1);
        }
      }
    }
    __syncthreads();
    // ---- mm2: acc += A2(64x320) @ wb(320x128); bf reused for both row tiles
    for (int s2 = 0; s2 < 20; ++s2) {
      short8 bf = wb8[((hf * 20 + s2) * 4 + wu) * 64 + l];
      short8 af0 = A2r[(2 * s2 + hh) * 64 + m];
      short8 af1 = A2r[(2 * s2 + hh) * 64 + 32 + m];
      acc0 = __builtin_amdgcn_mfma_f32_32x32x16_bf16(af0, bf, acc0, 0, 0, 0);
      acc1 = __builtin_amdgcn_mfma_f32_32x32x16_bf16(af1, bf, acc1, 0, 0, 0);
    }
    __syncthreads();
  }

  // ---- epilogue: acc -> C[64][128] (C/D: col=lane&31, row=(r&3)+8*(r>>2)+4*hh)
  float gb = glob[b];
  int g = wu * 32 + m;
  float br = (g < 117) ? b_reg[g] : 0.f;
  #pragma unroll
  for (int reg = 0; reg < 16; ++reg) {
    int n = (reg & 3) + 8 * (reg >> 2) + 4 * hh;
    C[n * 128 + g] = fmaxf(acc0[reg] + br + gb, 0.f);
    C[(n + 32) * 128 + g] = fmaxf(acc1[reg] + br + gb, 0.f);
  }
  __syncthreads();

  // spot partials FIRST (before bulk global stores; barrier sees no stores)
  {
    int half = tid >> 7, t = tid & 127;
    float s = 0.f;
    #pragma unroll 8
    for (int n = 0; n < 32; ++n) s += C[(half * 32 + n) * 128 + t];
    red[half * 128 + t] = s;
  }
  __syncthreads();
  if (tid < 128)
    spotp[(size_t)(b * 8 + tile) * 128 + tid] = red[tid] + red[128 + tid];

  // coalesced contiguous streams: cell chunk (29952 B) + out1 chunk (glob bcast)
  size_t rowbase = (size_t)(b * 512 + n0);
  float* cellchunk = out + CELL_OUT_OFF + rowbase * 117;
  #pragma unroll
  for (int i = 0; i < 30; ++i) {
    int idx = i * 256 + tid;
    if (idx < 7488) {
      int n = idx / 117;
      int gg = idx - n * 117;
      cellchunk[idx] = C[n * 128 + gg];
    }
  }
  float4 gv = make_float4(gb, gb, gb, gb);
  float4* o1v = (float4*)(out + OUT1_OUT_OFF + rowbase * 117);
  #pragma unroll
  for (int i = 0; i < 8; ++i) {
    int idx = i * 256 + tid;
    if (idx < 1872) o1v[idx] = gv;
  }
}

// spot[b][g] = sum of 8 tile partials
__global__ __launch_bounds__(256) void spot_reduce(
    const float* __restrict__ spotp, float* __restrict__ out) {
  int idx = blockIdx.x * 256 + threadIdx.x;   // exactly 117*256 = 29952
  int b = idx / 117;
  int g = idx - b * 117;
  float s = 0.f;
  #pragma unroll
  for (int t = 0; t < 8; ++t) s += spotp[(size_t)(b * 8 + t) * 128 + g];
  out[SPOT_OUT_OFF + idx] = s;
}

extern "C" void kernel_launch(void* const* d_in, const int* in_sizes, int n_in,
                              void* d_out, int out_size, void* d_ws, size_t ws_size,
                              hipStream_t stream) {
  const float* images      = (const float*)d_in[0];
  const float* spot_images = (const float*)d_in[1];
  // d_in[2] = gene_expression (unused by the reference)
  const float* W_emph = (const float*)d_in[3];
  const float* b_emph = (const float*)d_in[4];
  const float* W_reg  = (const float*)d_in[5];
  const float* b_reg  = (const float*)d_in[6];
  const float* W_patch = (const float*)d_in[7];
  const float* b_patch = (const float*)d_in[8];
  const float* W_glob  = (const float*)d_in[9];
  const float* b_glob  = (const float*)d_in[10];
  float* out = (float*)d_out;

  unsigned short* wb   = (unsigned short*)((char*)d_ws + WB_OFF);
  unsigned short* wbig = (unsigned short*)((char*)d_ws + WBIG_OFF);
  float* glob  = (float*)((char*)d_ws + GLOB_OFF);
  float* spotp = (float*)((char*)d_ws + SPOT_OFF);

  prep_kernel<<<496, 128, 0, stream>>>(spot_images, W_patch, b_patch, W_glob,
                                       b_glob, W_reg, W_emph, b_emph, wb, wbig,
                                       glob);
  main_kernel<<<2048, 256, 0, stream>>>(images, b_reg, wb, wbig, glob, out,
                                        spotp);
  spot_reduce<<<117, 256, 0, stream>>>(spotp, out);
}